// Round 2
// baseline (46662.341 us; speedup 1.0000x reference)
//
#include <hip/hip_runtime.h>
#include <hip/hip_fp16.h>

#define NT 512
#define TRAJ 4
#define RC 6   // resident chunks (k < 8*RC held in VGPRs)

constexpr int Lk = 200;
constexpr int NSTEPS = 100;

typedef float f32x2 __attribute__((ext_vector_type(2)));

#if __has_builtin(__builtin_elementwise_fma)
#define FMA2(a, b, c) __builtin_elementwise_fma((a), (b), (c))
#else
static __device__ __forceinline__ f32x2 fma2_(f32x2 a, f32x2 b, f32x2 c) {
    c.x = fmaf(a.x, b.x, c.x); c.y = fmaf(a.y, b.y, c.y); return c;
}
#define FMA2 fma2_
#endif

// Stable softplus, matches jax.nn.softplus in fp32: max(x,0) + log1p(exp(-|x|))
__device__ __forceinline__ float sp_act(float x) {
    return fmaxf(x, 0.0f) + log1pf(expf(-fabsf(x)));
}

// half2 (as uint32) -> f32x2
__device__ __forceinline__ f32x2 cvt2(unsigned int u) {
    union { unsigned int u; __half2 h; } x;
    x.u = u;
    float2 f = __half22float2(x.h);
    f32x2 r; r.x = f.x; r.y = f.y;
    return r;
}

// pack fW3 [2048][128] fp32 -> wP [64][2048] half2, wP[kp][n] = (fW3[n][2kp], fW3[n][2kp+1])
__global__ void fw3_pack(const float* __restrict__ w, __half2* __restrict__ wP) {
    int idx = blockIdx.x * 256 + threadIdx.x;   // 0 .. 131071
    int kp = idx >> 11;       // 0..63
    int n  = idx & 2047;      // 0..2047
    const float2 v = *(const float2*)(w + n * 128 + 2 * kp);
    wP[idx] = __halves2half2(__float2half_rn(v.x), __float2half_rn(v.y));
}

// Stage global weight W[O][I] (row-major) into LDS transposed T[I][O].
template<int O, int I>
__device__ __forceinline__ void stage_T(const float* __restrict__ g, float* __restrict__ T) {
    for (int base = threadIdx.x * 4; base < O * I; base += NT * 4) {
        const float4 w = *(const float4*)(g + base);
        const int o = base / I;
        const int i = base % I;
        T[(i + 0) * O + o] = w.x;
        T[(i + 1) * O + o] = w.y;
        T[(i + 2) * O + o] = w.z;
        T[(i + 3) * O + o] = w.w;
    }
}

// out[t][o] = act(bias[o] + sum_i in[t][i] * T[i][o]); k-paired for v_pk_fma_f32.
template<int I, int O, int ACT>
__device__ __forceinline__ void mlp_layer(const float* __restrict__ T,
                                          const float* __restrict__ bias,
                                          const float* __restrict__ in, int inStride,
                                          float* __restrict__ out, int outStride) {
    const int tid = threadIdx.x;
    constexpr int TOT = TRAJ * O;
    for (int e = tid; e < TOT; e += NT) {
        const int t = e / O;
        const int o = e % O;
        const float* inr = in + t * inStride;
        f32x2 a2; a2.x = bias[o]; a2.y = 0.0f;
        #pragma unroll 4
        for (int i = 0; i < I; i += 2) {
            f32x2 xv; xv.x = inr[i];        xv.y = inr[i + 1];
            f32x2 wv; wv.x = T[i * O + o];  wv.y = T[(i + 1) * O + o];
            a2 = FMA2(xv, wv, a2);
        }
        float acc = a2.x + a2.y;
        if (ACT == 1) acc = sp_act(acc);
        else if (ACT == 2) acc = fmaxf(acc, 0.0f);
        out[t * outStride + o] = acc;
    }
}

// One vector-field eval + fused state update (done by the einsum-owner lanes).
// wk=true  (k1): kout[i] = k;        yout[i] = ybase[i] + cb*k        (cb = dt)
// wk=false (k2):                     yout[i] = ybase[i] + ca*(kaux[i]+k)  (ca = dt/2)
__device__ __forceinline__ void evalvf(float t,
                                       const float* __restrict__ yin,
                                       float* __restrict__ kout, bool wk,
                                       const float* __restrict__ kaux,
                                       const float* __restrict__ ybase,
                                       float* __restrict__ yout,
                                       float ca, float cb,
                                       const float* __restrict__ wT1,
                                       const float* __restrict__ wT2,
                                       const float* __restrict__ fb1s,
                                       const float* __restrict__ fb2s,
                                       float* __restrict__ h1s,
                                       float* __restrict__ h2s,
                                       float* __restrict__ dXs,
                                       const float* __restrict__ ts,
                                       const float* __restrict__ coef_b,
                                       const float* __restrict__ coef_c,
                                       const float* __restrict__ coef_d,
                                       int bbase,
                                       const uint4* __restrict__ wph,
                                       const uint4* __restrict__ res,
                                       float4 fb3r)
{
    const int tid = threadIdx.x;

    // cubic-spline derivative dX/dt at scalar time t
    if (tid < TRAJ * 32) {
        int i = (int)floorf(t);
        i = min(max(i, 0), Lk - 2);
        const float frac = t - ts[i];
        const int tt = tid >> 5, d = tid & 31;
        const size_t off = ((size_t)(bbase + tt) * 199 + (size_t)i) * 32 + d;
        dXs[tid] = coef_b[off] + frac * (2.0f * coef_c[off] + 3.0f * frac * coef_d[off]);
    }

    // Pre-issue streamed chunks RC..RC+2 (3-deep rotating prefetch); latency hides
    // under the two small MLP layers.
    uint4 sbuf[3][4];
    #pragma unroll
    for (int q = 0; q < 3; ++q)
        #pragma unroll
        for (int i = 0; i < 4; ++i)
            sbuf[q][i] = wph[(4 * (RC + q) + i) * 512];

    mlp_layer<64, 128, 1>(wT1, fb1s, yin, 64, h1s, 128);
    __syncthreads();
    mlp_layer<128, 128, 1>(wT2, fb2s, h1s, 128, h2s, 128);
    __syncthreads();

    // Big layer: thread owns n = 4*tid+j. Accumulate k-pairs with packed FMA:
    // acc[j][t] = (partial over even-slot k, partial over odd-slot k).
    f32x2 acc[4][TRAJ];
    #pragma unroll
    for (int t4 = 0; t4 < TRAJ; ++t4) {
        acc[0][t4].x = fb3r.x; acc[0][t4].y = 0.f;
        acc[1][t4].x = fb3r.y; acc[1][t4].y = 0.f;
        acc[2][t4].x = fb3r.z; acc[2][t4].y = 0.f;
        acc[3][t4].x = fb3r.w; acc[3][t4].y = 0.f;
    }

    #pragma unroll
    for (int c = 0; c < 16; ++c) {
        const int slot = (c >= RC) ? (c - RC) % 3 : 0;
        // convert this chunk's weights: wv[i][j] = (w[nj][2kp], w[nj][2kp+1]), kp = 4c+i
        f32x2 wv[4][4];
        #pragma unroll
        for (int i = 0; i < 4; ++i) {
            uint4 W;
            if (c < RC) W = res[4 * c + i];
            else        W = sbuf[slot][i];
            wv[i][0] = cvt2(W.x); wv[i][1] = cvt2(W.y);
            wv[i][2] = cvt2(W.z); wv[i][3] = cvt2(W.w);
        }
        // rotate prefetch: reuse this slot for chunk c+3
        if (c >= RC && c + 3 < 16) {
            #pragma unroll
            for (int i = 0; i < 4; ++i)
                sbuf[slot][i] = wph[(4 * (c + 3) + i) * 512];
        }
        #pragma unroll
        for (int t4 = 0; t4 < TRAJ; ++t4) {
            const float4 ha = *(const float4*)(h2s + t4 * 128 + 8 * c);
            const float4 hb = *(const float4*)(h2s + t4 * 128 + 8 * c + 4);
            f32x2 hp[4];
            hp[0].x = ha.x; hp[0].y = ha.y;
            hp[1].x = ha.z; hp[1].y = ha.w;
            hp[2].x = hb.x; hp[2].y = hb.y;
            hp[3].x = hb.z; hp[3].y = hb.w;
            #pragma unroll
            for (int i = 0; i < 4; ++i) {
                acc[0][t4] = FMA2(wv[i][0], hp[i], acc[0][t4]);
                acc[1][t4] = FMA2(wv[i][1], hp[i], acc[1][t4]);
                acc[2][t4] = FMA2(wv[i][2], hp[i], acc[2][t4]);
                acc[3][t4] = FMA2(wv[i][3], hp[i], acc[3][t4]);
            }
        }
    }

    // einsum over d: n = 4*tid+j => h = tid>>3, d = 4*(tid&7)+j. 8-lane reduce per h.
    const int dbase = 4 * (tid & 7);
    float part[TRAJ];
    #pragma unroll
    for (int t4 = 0; t4 < TRAJ; ++t4) {
        const float4 dx = *(const float4*)(dXs + t4 * 32 + dbase);
        part[t4] = (acc[0][t4].x + acc[0][t4].y) * dx.x +
                   (acc[1][t4].x + acc[1][t4].y) * dx.y +
                   (acc[2][t4].x + acc[2][t4].y) * dx.z +
                   (acc[3][t4].x + acc[3][t4].y) * dx.w;
    }
    #pragma unroll
    for (int m = 1; m < 8; m <<= 1) {
        #pragma unroll
        for (int t4 = 0; t4 < TRAJ; ++t4) part[t4] += __shfl_xor(part[t4], m, 64);
    }
    if ((tid & 7) == 0) {
        const int h = tid >> 3;
        #pragma unroll
        for (int t4 = 0; t4 < TRAJ; ++t4) {
            const int idx = t4 * 64 + h;
            const float kq = part[t4];
            if (wk) { kout[idx] = kq; yout[idx] = ybase[idx] + cb * kq; }
            else    {                 yout[idx] = ybase[idx] + ca * (kaux[idx] + kq); }
        }
    }
    __syncthreads();
}

__global__ __launch_bounds__(NT, 1)
void cde_kernel(const float* __restrict__ ts,
                const float* __restrict__ coef_d, const float* __restrict__ coef_c,
                const float* __restrict__ coef_b, const float* __restrict__ coef_a,
                const float* __restrict__ iW1, const float* __restrict__ ib1,
                const float* __restrict__ iW2, const float* __restrict__ ib2,
                const float* __restrict__ iW3, const float* __restrict__ ib3,
                const float* __restrict__ fW1, const float* __restrict__ fb1,
                const float* __restrict__ fW2, const float* __restrict__ fb2,
                const float* __restrict__ fb3,
                const float* __restrict__ dW1, const float* __restrict__ db1,
                const float* __restrict__ dW2, const float* __restrict__ db2,
                const float* __restrict__ dW3, const float* __restrict__ db3,
                const __half2* __restrict__ fW3P,
                float* __restrict__ outp)
{
    // weight region is a union across phases: init (112KB) / main (96KB) / decoder (104KB)
    __shared__ float wreg[28672];
    __shared__ float h1s[TRAJ * 128], h2s[TRAJ * 128];
    __shared__ float ys[TRAJ * 64], ys2[TRAJ * 64], k1s[TRAJ * 64];
    __shared__ float dXs[TRAJ * 32], a0s[TRAJ * 32];
    __shared__ float fb1s[128], fb2s[128];

    const int tid = threadIdx.x;
    const int bbase = blockIdx.x * TRAJ;

    const float ts0 = ts[0];
    const float dt = (ts[Lk - 1] - ts0) / (float)NSTEPS;
    const float hdt = 0.5f * dt;
    const float4 fb3r = *((const float4*)fb3 + tid);         // n = 4*tid .. 4*tid+3
    const uint4* wph = (const uint4*)fW3P + tid;             // row stride 512 uint4

    // Resident fW3 slice: chunks 0..RC-1 (k < 8*RC), 4*RC uint4 = 16*RC VGPRs.
    uint4 res[4 * RC];
    #pragma unroll
    for (int j = 0; j < 4 * RC; ++j) res[j] = wph[j * 512];

    // ---- initial condition: y0 = sp(MLP_i(coef_a[:,0,:])) ----
    if (tid < TRAJ * 32) {
        const int t = tid >> 5, d = tid & 31;
        a0s[t * 32 + d] = coef_a[((size_t)(bbase + t) * 199) * 32 + d];
    }
    stage_T<128, 32>(iW1, wreg);                       // iT1 [32][128]
    stage_T<128, 128>(iW2, wreg + 32 * 128);           // iT2 [128][128]
    stage_T<64, 128>(iW3, wreg + 32 * 128 + 128 * 128);// iT3 [128][64]
    if (tid < 128) { fb1s[tid] = fb1[tid]; fb2s[tid] = fb2[tid]; }
    __syncthreads();
    mlp_layer<32, 128, 1>(wreg, ib1, a0s, 32, h1s, 128);
    __syncthreads();
    mlp_layer<128, 128, 1>(wreg + 32 * 128, ib2, h1s, 128, h2s, 128);
    __syncthreads();
    mlp_layer<128, 64, 1>(wreg + 32 * 128 + 128 * 128, ib3, h2s, 128, ys, 64);
    __syncthreads();

    // ---- stage vector-field small weights (resident for all 200 evals) ----
    stage_T<128, 64>(fW1, wreg);                       // wT1 [64][128]
    stage_T<128, 128>(fW2, wreg + 64 * 128);           // wT2 [128][128]
    __syncthreads();

    // ---- Heun, 100 steps = 200 evals; state update fused into einsum owners ----
    for (int e = 0; e < 2 * NSTEPS; ++e) {
        const int step = e >> 1;
        const bool k2 = e & 1;
        const float t = ts0 + (float)step * dt + (k2 ? dt : 0.0f);
        evalvf(t,
               k2 ? ys2 : ys,          // yin
               k1s, !k2,               // kout, write-k flag
               k1s,                    // kaux (read only on k2)
               ys,                     // ybase
               k2 ? ys : ys2,          // yout
               hdt, dt,
               wreg, wreg + 64 * 128, fb1s, fb2s, h1s, h2s, dXs,
               ts, coef_b, coef_c, coef_d, bbase, wph, res, fb3r);
    }

    // ---- decoder: Linear->relu->Linear->relu->Linear ----
    stage_T<128, 64>(dW1, wreg);                          // dT1 [64][128]
    stage_T<128, 128>(dW2, wreg + 64 * 128);              // dT2 [128][128]
    stage_T<16, 128>(dW3, wreg + 64 * 128 + 128 * 128);   // dT3 [128][16]
    __syncthreads();
    mlp_layer<64, 128, 2>(wreg, db1, ys, 64, h1s, 128);
    __syncthreads();
    mlp_layer<128, 128, 2>(wreg + 64 * 128, db2, h1s, 128, h2s, 128);
    __syncthreads();
    mlp_layer<128, 16, 0>(wreg + 64 * 128 + 128 * 128, db3, h2s, 128,
                          outp + (size_t)bbase * 16, 16);
}

extern "C" void kernel_launch(void* const* d_in, const int* in_sizes, int n_in,
                              void* d_out, int out_size, void* d_ws, size_t ws_size,
                              hipStream_t stream) {
    (void)in_sizes; (void)n_in; (void)out_size; (void)ws_size;
    const float* ts     = (const float*)d_in[0];
    const float* coef_d = (const float*)d_in[1];
    const float* coef_c = (const float*)d_in[2];
    const float* coef_b = (const float*)d_in[3];
    const float* coef_a = (const float*)d_in[4];
    const float* iW1 = (const float*)d_in[5];  const float* ib1 = (const float*)d_in[6];
    const float* iW2 = (const float*)d_in[7];  const float* ib2 = (const float*)d_in[8];
    const float* iW3 = (const float*)d_in[9];  const float* ib3 = (const float*)d_in[10];
    const float* fW1 = (const float*)d_in[11]; const float* fb1 = (const float*)d_in[12];
    const float* fW2 = (const float*)d_in[13]; const float* fb2 = (const float*)d_in[14];
    const float* fW3 = (const float*)d_in[15]; const float* fb3 = (const float*)d_in[16];
    const float* dW1 = (const float*)d_in[17]; const float* db1 = (const float*)d_in[18];
    const float* dW2 = (const float*)d_in[19]; const float* db2 = (const float*)d_in[20];
    const float* dW3 = (const float*)d_in[21]; const float* db3 = (const float*)d_in[22];

    __half2* fW3P = (__half2*)d_ws;   // 512 KB: fW3 packed fp16, [64 k-pairs][2048 n]

    fw3_pack<<<512, 256, 0, stream>>>(fW3, fW3P);
    cde_kernel<<<256, NT, 0, stream>>>(ts, coef_d, coef_c, coef_b, coef_a,
                                       iW1, ib1, iW2, ib2, iW3, ib3,
                                       fW1, fb1, fW2, fb2, fb3,
                                       dW1, db1, dW2, db2, dW3, db3,
                                       fW3P, (float*)d_out);
}

// Round 4
// 3627.303 us; speedup vs baseline: 12.8642x; 12.8642x over previous
//
#include <hip/hip_runtime.h>

#define NT 512
#define TRAJ 4

constexpr int Lk = 200;
constexpr int NSTEPS = 100;

typedef float f32x2 __attribute__((ext_vector_type(2)));
typedef float f32x4 __attribute__((ext_vector_type(4)));
typedef short s16x8 __attribute__((ext_vector_type(8)));

#if __has_builtin(__builtin_elementwise_fma)
#define FMA2(a, b, c) __builtin_elementwise_fma((a), (b), (c))
#else
static __device__ __forceinline__ f32x2 fma2_(f32x2 a, f32x2 b, f32x2 c) {
    c.x = fmaf(a.x, b.x, c.x); c.y = fmaf(a.y, b.y, c.y); return c;
}
#define FMA2 fma2_
#endif

// Stable softplus, matches jax.nn.softplus in fp32: max(x,0) + log1p(exp(-|x|))
__device__ __forceinline__ float sp_act(float x) {
    return fmaxf(x, 0.0f) + log1pf(expf(-fabsf(x)));
}

// fp32 -> bf16 with round-to-nearest-even
__device__ __forceinline__ unsigned short f2bf(float f) {
    union { float f; unsigned int u; } v; v.f = f;
    unsigned int u = v.u + 0x7FFFu + ((v.u >> 16) & 1u);
    return (unsigned short)(u >> 16);
}

// Pack fW3 [2048][128] fp32 -> bf16 B-fragments for mfma_f32_16x16x32_bf16.
// Slot s = (tile*4 + ks)*64 + lane holds 8 bf16: B[k = ks*32 + (lane>>4)*8 + j][n = tile*16 + (lane&15)]
// so each wave's (tile,ks) load is 64 consecutive 16B chunks (fully coalesced).
__global__ void fw3_packb(const float* __restrict__ w, unsigned short* __restrict__ p) {
    const int s = blockIdx.x * 256 + threadIdx.x;   // 0..32767
    const int tg = s >> 8;
    const int ks = (s >> 6) & 3;
    const int l  = s & 63;
    const int n  = tg * 16 + (l & 15);
    const int k0 = ks * 32 + (l >> 4) * 8;
    unsigned short out[8];
    #pragma unroll
    for (int j = 0; j < 8; ++j) out[j] = f2bf(w[n * 128 + k0 + j]);
    *(uint4*)(p + (size_t)s * 8) = *(const uint4*)out;
}

// Stage global weight W[O][I] (row-major) into LDS transposed T[I][O].
template<int O, int I>
__device__ __forceinline__ void stage_T(const float* __restrict__ g, float* __restrict__ T) {
    for (int base = threadIdx.x * 4; base < O * I; base += NT * 4) {
        const float4 w = *(const float4*)(g + base);
        const int o = base / I;
        const int i = base % I;
        T[(i + 0) * O + o] = w.x;
        T[(i + 1) * O + o] = w.y;
        T[(i + 2) * O + o] = w.z;
        T[(i + 3) * O + o] = w.w;
    }
}

// out[t][o] = act(bias[o] + sum_i in[t][i] * T[i][o]); ACT: 0=none,1=softplus,2=relu
template<int I, int O, int ACT>
__device__ __forceinline__ void mlp_layer(const float* __restrict__ T,
                                          const float* __restrict__ bias,
                                          const float* __restrict__ in, int inStride,
                                          float* __restrict__ out, int outStride) {
    const int tid = threadIdx.x;
    constexpr int TOT = TRAJ * O;
    for (int e = tid; e < TOT; e += NT) {
        const int t = e / O;
        const int o = e % O;
        const float* inr = in + t * inStride;
        f32x2 a2; a2.x = bias[o]; a2.y = 0.0f;
        #pragma unroll 4
        for (int i = 0; i < I; i += 2) {
            f32x2 xv; xv.x = inr[i];        xv.y = inr[i + 1];
            f32x2 wv; wv.x = T[i * O + o];  wv.y = T[(i + 1) * O + o];
            a2 = FMA2(xv, wv, a2);
        }
        float acc = a2.x + a2.y;
        if (ACT == 1) acc = sp_act(acc);
        else if (ACT == 2) acc = fmaxf(acc, 0.0f);
        out[t * outStride + o] = acc;
    }
}

// layer2 of the vector field: I=O=128, softplus, bf16 output (A-operand for MFMA)
__device__ __forceinline__ void mlp_layer2_bf(const float* __restrict__ T,
                                              const float* __restrict__ bias,
                                              const float* __restrict__ in,
                                              unsigned short* __restrict__ out) {
    const int tid = threadIdx.x;
    const int t = tid >> 7, o = tid & 127;
    const float* inr = in + t * 128;
    f32x2 a2; a2.x = bias[o]; a2.y = 0.0f;
    #pragma unroll 4
    for (int i = 0; i < 128; i += 2) {
        f32x2 xv; xv.x = inr[i];          xv.y = inr[i + 1];
        f32x2 wv; wv.x = T[i * 128 + o];  wv.y = T[(i + 1) * 128 + o];
        a2 = FMA2(xv, wv, a2);
    }
    out[t * 128 + o] = f2bf(sp_act(a2.x + a2.y));
}

// One vector-field eval + fused Heun state update.
// wk=true  (k1): kout[i] = k;  yout[i] = ybase[i] + cb*k            (cb = dt)
// wk=false (k2):               yout[i] = ybase[i] + ca*(kaux[i]+k)  (ca = dt/2)
__device__ __forceinline__ void evalvf(float t,
                                       const float* __restrict__ yin,
                                       float* __restrict__ kout, bool wk,
                                       const float* __restrict__ kaux,
                                       const float* __restrict__ ybase,
                                       float* __restrict__ yout,
                                       float ca, float cb,
                                       const float* __restrict__ wT1,
                                       const float* __restrict__ wT2,
                                       const float* __restrict__ fb1s,
                                       const float* __restrict__ fb2s,
                                       const float* __restrict__ fb3s,
                                       float* __restrict__ h1s,
                                       unsigned short* __restrict__ h2bf,
                                       float* __restrict__ dXs,
                                       const float* __restrict__ ts,
                                       const float* __restrict__ coef_b,
                                       const float* __restrict__ coef_c,
                                       const float* __restrict__ coef_d,
                                       int bbase,
                                       const unsigned short* __restrict__ fW3B)
{
    const int tid  = threadIdx.x;
    const int lane = tid & 63;
    const int wave = tid >> 6;

    // cubic-spline derivative dX/dt at scalar time t
    if (tid < TRAJ * 32) {
        int i = (int)floorf(t);
        i = min(max(i, 0), Lk - 2);
        const float frac = t - ts[i];
        const int tt = tid >> 5, d = tid & 31;
        const size_t off = ((size_t)(bbase + tt) * 199 + (size_t)i) * 32 + d;
        dXs[tid] = coef_b[off] + frac * (2.0f * coef_c[off] + 3.0f * frac * coef_d[off]);
    }

    // Pre-issue B-fragments of tile 0 — latency hides under the two small layers.
    const uint4* wq = (const uint4*)fW3B + lane;
    uint4 cur[4], nxt[4];
    #pragma unroll
    for (int ks = 0; ks < 4; ++ks) cur[ks] = wq[((wave * 16 + 0) * 4 + ks) * 64];

    mlp_layer<64, 128, 1>(wT1, fb1s, yin, 64, h1s, 128);
    __syncthreads();
    mlp_layer2_bf(wT2, fb2s, h1s, h2bf);
    __syncthreads();

    // A-fragments: lane supplies A[row = lane&15][k = ks*32 + (lane>>4)*8 + j].
    // Rows 0..3 are real trajectories; rows 4..15 read zeroed LDS (outputs discarded).
    s16x8 afrag[4];
    #pragma unroll
    for (int ks = 0; ks < 4; ++ks)
        afrag[ks] = *(const s16x8*)(h2bf + (lane & 15) * 128 + ks * 32 + (lane >> 4) * 8);

    // dX values this lane needs: d = (tile&1)*16 + (lane&15)
    float dx0[4], dx1[4];
    #pragma unroll
    for (int r = 0; r < 4; ++r) {
        dx0[r] = dXs[r * 32 + (lane & 15)];
        dx1[r] = dXs[r * 32 + 16 + (lane & 15)];
    }

    float psum[8][4];
    #pragma unroll
    for (int h = 0; h < 8; ++h)
        #pragma unroll
        for (int r = 0; r < 4; ++r) psum[h][r] = 0.0f;

    #pragma unroll
    for (int tile = 0; tile < 16; ++tile) {
        if (tile < 15) {
            #pragma unroll
            for (int ks = 0; ks < 4; ++ks)
                nxt[ks] = wq[((wave * 16 + tile + 1) * 4 + ks) * 64];
        }
        f32x4 acc = {0.f, 0.f, 0.f, 0.f};
        #pragma unroll
        for (int ks = 0; ks < 4; ++ks) {
            const s16x8 b = *(const s16x8*)&cur[ks];
            acc = __builtin_amdgcn_mfma_f32_16x16x32_bf16(afrag[ks], b, acc, 0, 0, 0);
        }
        // fused einsum: lane&15 -> n = tile*16+(lane&15); d = (tile&1)*16+(lane&15); traj = reg r
        const float bb = fb3s[(wave * 16 + tile) * 16 + (lane & 15)];
        #pragma unroll
        for (int r = 0; r < 4; ++r) {
            const float g = acc[r] + bb;
            if (tile & 1) psum[tile >> 1][r] = fmaf(g, dx1[r], psum[tile >> 1][r]);
            else          psum[tile >> 1][r] = fmaf(g, dx0[r], psum[tile >> 1][r]);
        }
        #pragma unroll
        for (int ks = 0; ks < 4; ++ks) cur[ks] = nxt[ks];
    }

    // Reduce over d: butterfly within each 16-lane group (real data in lanes 0-15).
    #pragma unroll
    for (int m = 1; m < 16; m <<= 1)
        #pragma unroll
        for (int h = 0; h < 8; ++h)
            #pragma unroll
            for (int r = 0; r < 4; ++r)
                psum[h][r] += __shfl_xor(psum[h][r], m, 64);

    // Owner lanes write k and the fused Heun update. h global = wave*8 + h.
    #pragma unroll
    for (int h = 0; h < 8; ++h) {
        if (lane == h) {
            const int hg = wave * 8 + h;
            #pragma unroll
            for (int r = 0; r < 4; ++r) {
                const int idx = r * 64 + hg;
                const float kq = psum[h][r];
                if (wk) { kout[idx] = kq; yout[idx] = ybase[idx] + cb * kq; }
                else    {                 yout[idx] = ybase[idx] + ca * (kaux[idx] + kq); }
            }
        }
    }
    __syncthreads();
}

__global__ __launch_bounds__(NT, 1)
void cde_kernel(const float* __restrict__ ts,
                const float* __restrict__ coef_d, const float* __restrict__ coef_c,
                const float* __restrict__ coef_b, const float* __restrict__ coef_a,
                const float* __restrict__ iW1, const float* __restrict__ ib1,
                const float* __restrict__ iW2, const float* __restrict__ ib2,
                const float* __restrict__ iW3, const float* __restrict__ ib3,
                const float* __restrict__ fW1, const float* __restrict__ fb1,
                const float* __restrict__ fW2, const float* __restrict__ fb2,
                const float* __restrict__ fb3,
                const float* __restrict__ dW1, const float* __restrict__ db1,
                const float* __restrict__ dW2, const float* __restrict__ db2,
                const float* __restrict__ dW3, const float* __restrict__ db3,
                const unsigned short* __restrict__ fW3B,
                float* __restrict__ outp)
{
    // wreg is a phase-union. Init: iT1+iT2+iT3 = 28672 floats (all of it).
    // Main: wT1(8192) + wT2(16384) = 24576, then fb3s (2048 f) at +24576 and
    // h2bf (2048 bf16 = 1024 f) at +26624 — staged AFTER init. Total LDS = 123904 B,
    // identical to the round-0/1 configuration that is proven to load and run.
    __shared__ __align__(16) float wreg[28672];
    __shared__ float h1s[TRAJ * 128], h2s[TRAJ * 128];
    __shared__ float ys[TRAJ * 64], ys2[TRAJ * 64], k1s[TRAJ * 64];
    __shared__ float dXs[TRAJ * 32], a0s[TRAJ * 32];
    __shared__ float fb1s[128], fb2s[128];

    float* const fb3s = wreg + 24576;                         // [2048]
    unsigned short* const h2bf = (unsigned short*)(wreg + 26624); // [16*128] bf16

    const int tid = threadIdx.x;
    const int bbase = blockIdx.x * TRAJ;

    const float ts0 = ts[0];
    const float dt = (ts[Lk - 1] - ts0) / (float)NSTEPS;
    const float hdt = 0.5f * dt;

    // ---- initial condition: y0 = sp(MLP_i(coef_a[:,0,:])) ----
    if (tid < TRAJ * 32) {
        const int t = tid >> 5, d = tid & 31;
        a0s[t * 32 + d] = coef_a[((size_t)(bbase + t) * 199) * 32 + d];
    }
    stage_T<128, 32>(iW1, wreg);                       // iT1 [32][128]
    stage_T<128, 128>(iW2, wreg + 32 * 128);           // iT2 [128][128]
    stage_T<64, 128>(iW3, wreg + 32 * 128 + 128 * 128);// iT3 [128][64]
    if (tid < 128) { fb1s[tid] = fb1[tid]; fb2s[tid] = fb2[tid]; }
    __syncthreads();
    mlp_layer<32, 128, 1>(wreg, ib1, a0s, 32, h1s, 128);
    __syncthreads();
    mlp_layer<128, 128, 1>(wreg + 32 * 128, ib2, h1s, 128, h2s, 128);
    __syncthreads();
    mlp_layer<128, 64, 1>(wreg + 32 * 128 + 128 * 128, ib3, h2s, 128, ys, 64);
    __syncthreads();

    // ---- stage vector-field weights + fb3 + zero A-pad rows (resident for 200 evals) ----
    stage_T<128, 64>(fW1, wreg);                       // wT1 [64][128]
    stage_T<128, 128>(fW2, wreg + 64 * 128);           // wT2 [128][128]
    for (int i = tid * 4; i < 2048; i += NT * 4)
        *(float4*)(fb3s + i) = *(const float4*)(fb3 + i);
    for (int i = tid; i < 16 * 128; i += NT) h2bf[i] = 0;
    __syncthreads();

    // ---- Heun, 100 steps = 200 evals; state update fused into owner lanes ----
    for (int e = 0; e < 2 * NSTEPS; ++e) {
        const int step = e >> 1;
        const bool k2 = e & 1;
        const float t = ts0 + (float)step * dt + (k2 ? dt : 0.0f);
        evalvf(t,
               k2 ? ys2 : ys,          // yin
               k1s, !k2,               // kout, write-k flag
               k1s,                    // kaux (read only on k2)
               ys,                     // ybase
               k2 ? ys : ys2,          // yout
               hdt, dt,
               wreg, wreg + 64 * 128, fb1s, fb2s, fb3s, h1s, h2bf, dXs,
               ts, coef_b, coef_c, coef_d, bbase, fW3B);
    }

    // ---- decoder: Linear->relu->Linear->relu->Linear ----
    stage_T<128, 64>(dW1, wreg);                          // dT1 [64][128]
    stage_T<128, 128>(dW2, wreg + 64 * 128);              // dT2 [128][128]
    stage_T<16, 128>(dW3, wreg + 64 * 128 + 128 * 128);   // dT3 [128][16] (overlaps dead fb3s)
    __syncthreads();
    mlp_layer<64, 128, 2>(wreg, db1, ys, 64, h1s, 128);
    __syncthreads();
    mlp_layer<128, 128, 2>(wreg + 64 * 128, db2, h1s, 128, h2s, 128);
    __syncthreads();
    mlp_layer<128, 16, 0>(wreg + 64 * 128 + 128 * 128, db3, h2s, 128,
                          outp + (size_t)bbase * 16, 16);
}

extern "C" void kernel_launch(void* const* d_in, const int* in_sizes, int n_in,
                              void* d_out, int out_size, void* d_ws, size_t ws_size,
                              hipStream_t stream) {
    (void)in_sizes; (void)n_in; (void)out_size; (void)ws_size;
    const float* ts     = (const float*)d_in[0];
    const float* coef_d = (const float*)d_in[1];
    const float* coef_c = (const float*)d_in[2];
    const float* coef_b = (const float*)d_in[3];
    const float* coef_a = (const float*)d_in[4];
    const float* iW1 = (const float*)d_in[5];  const float* ib1 = (const float*)d_in[6];
    const float* iW2 = (const float*)d_in[7];  const float* ib2 = (const float*)d_in[8];
    const float* iW3 = (const float*)d_in[9];  const float* ib3 = (const float*)d_in[10];
    const float* fW1 = (const float*)d_in[11]; const float* fb1 = (const float*)d_in[12];
    const float* fW2 = (const float*)d_in[13]; const float* fb2 = (const float*)d_in[14];
    const float* fW3 = (const float*)d_in[15]; const float* fb3 = (const float*)d_in[16];
    const float* dW1 = (const float*)d_in[17]; const float* db1 = (const float*)d_in[18];
    const float* dW2 = (const float*)d_in[19]; const float* db2 = (const float*)d_in[20];
    const float* dW3 = (const float*)d_in[21]; const float* db3 = (const float*)d_in[22];

    unsigned short* fW3B = (unsigned short*)d_ws;   // 512 KB: fW3 as bf16 B-fragments

    fw3_packb<<<128, 256, 0, stream>>>(fW3, fW3B);
    cde_kernel<<<256, NT, 0, stream>>>(ts, coef_d, coef_c, coef_b, coef_a,
                                       iW1, ib1, iW2, ib2, iW3, ib3,
                                       fW1, fb1, fW2, fb2, fb3,
                                       dW1, db1, dW2, db2, dW3, db3,
                                       fW3B, (float*)d_out);
}